// Round 18
// baseline (389.921 us; speedup 1.0000x reference)
//
#include <hip/hip_runtime.h>
#include <cstdint>
#include <cstddef>

// Extractor_N2V folded: g = seg_sum(h[src],dst)/deg + eps1*h  (bf16 storage)
// BN stats via y = g@W1^T MFMA pass reduced to per-channel sum/sumsq;
// out = g @ M^T + c with M = W2 diag(s) W1 (bf16). CSR via bucket sort.
// R18: k_out reverted to R15 epilogue (best measured, 0 conflicts), split in
// two for profiling visibility; stats2+matM fused (k_smm); yreduce non-atomic.

#define IN_DIM 128
#define H_DIM 256
#define NPB 256
#define MAXB 1792
#define FB_CAP 6400
#define BS_CAP 10240
#define YG 16

typedef unsigned int uint32;
typedef unsigned short ushort;
typedef __attribute__((ext_vector_type(8))) short short8;
typedef __attribute__((ext_vector_type(4))) float f32x4;
typedef __attribute__((ext_vector_type(4))) uint32 u32x4;

union U16B { uint4 u; short8 s; };

static inline size_t align256(size_t x){ return (x + 255) & ~(size_t)255; }

__device__ inline uint32 f2bf(float f){
  uint32 u = __float_as_uint(f);
  return (u + 0x7FFFu + ((u >> 16) & 1u)) >> 16;   // RNE
}
__device__ inline float bflo(uint32 u){ return __uint_as_float(u << 16); }
__device__ inline float bfhi(uint32 u){ return __uint_as_float(u & 0xFFFF0000u); }

// ---- fused: h->hb (bf16), W1->W1b (bf16), bucket histogram (dst>>8)
__global__ __launch_bounds__(256) void k_prep(const float* __restrict__ h,
                        uint32* __restrict__ hb2, int n4,
                        const float* __restrict__ W1, uint32* __restrict__ W1b2,
                        const int* __restrict__ dst, int* __restrict__ gcount,
                        int E_, int B_) {
  __shared__ int lc[512];
  int t = threadIdx.x;
  int stride = gridDim.x*256;
  for (int i = blockIdx.x*256 + t; i < n4; i += stride) {
    u32x4 uv = __builtin_nontemporal_load((const u32x4*)h + i);
    uint32 lo = f2bf(__uint_as_float(uv.x)) | (f2bf(__uint_as_float(uv.y)) << 16);
    uint32 hi = f2bf(__uint_as_float(uv.z)) | (f2bf(__uint_as_float(uv.w)) << 16);
    ((uint2*)hb2)[i] = make_uint2(lo, hi);
  }
  for (int i = blockIdx.x*256 + t; i < 256*128/4; i += stride) {
    u32x4 uv = *((const u32x4*)W1 + i);
    uint32 lo = f2bf(__uint_as_float(uv.x)) | (f2bf(__uint_as_float(uv.y)) << 16);
    uint32 hi = f2bf(__uint_as_float(uv.z)) | (f2bf(__uint_as_float(uv.w)) << 16);
    ((uint2*)W1b2)[i] = make_uint2(lo, hi);
  }
  for (int j = t; j < B_; j += 256) lc[j] = 0;
  __syncthreads();
  int per = (E_ + gridDim.x - 1) / gridDim.x;
  int beg = blockIdx.x * per, end = min(beg + per, E_);
  for (int j = beg + t; j < end; j += 256)
    atomicAdd(&lc[__builtin_nontemporal_load(dst + j) >> 8], 1);
  __syncthreads();
  for (int j = t; j < B_; j += 256) { int v = lc[j]; if (v) atomicAdd(&gcount[j], v); }
}

// ---- exclusive scan of bucket counts
__global__ __launch_bounds__(256) void k_bscan(const int* __restrict__ gcount,
                        int* __restrict__ boff, int* __restrict__ gcursor,
                        int* __restrict__ row_ptr, int B_, int N_) {
  __shared__ int part[256];
  __shared__ int vals[MAXB];
  int t = threadIdx.x;
  int base = t * 7;
  int s = 0;
  #pragma unroll
  for (int k = 0; k < 7; k++) {
    int idx = base + k;
    int v = (idx < B_) ? gcount[idx] : 0;
    vals[idx < MAXB ? idx : MAXB-1] = s;
    s += v;
  }
  part[t] = s;
  __syncthreads();
  for (int off = 1; off < 256; off <<= 1) {
    int a = (t >= off) ? part[t - off] : 0;
    __syncthreads();
    part[t] += a;
    __syncthreads();
  }
  int pbase = (t > 0) ? part[t - 1] : 0;
  #pragma unroll
  for (int k = 0; k < 7; k++) {
    int idx = base + k;
    if (idx < B_) { int o = pbase + vals[idx]; boff[idx] = o; gcursor[idx] = o; }
  }
  if (t == 255) { boff[B_] = part[255]; row_ptr[N_] = part[255]; }
}

// ---- LDS counting-sort scatter: local sort, reserve chunk, burst chunk copy
__global__ __launch_bounds__(256) void k_bfill(const int* __restrict__ src,
                        const int* __restrict__ dst, int* __restrict__ gcursor,
                        uint32* __restrict__ pairs, int E_, int B_) {
  __shared__ uint32 sbuf[FB_CAP];
  __shared__ int lcnt[512];
  __shared__ int loff[512];
  __shared__ int lcur[512];
  __shared__ int gbase[512];
  __shared__ int part[256];
  int t = threadIdx.x;
  for (int i = t; i < 512; i += 256) lcnt[i] = 0;
  __syncthreads();
  int per = (E_ + gridDim.x - 1) / gridDim.x;
  int beg = blockIdx.x * per, end = min(beg + per, E_);
  for (int i = beg + t; i < end; i += 256)
    atomicAdd(&lcnt[__builtin_nontemporal_load(dst + i) >> 8], 1);
  __syncthreads();
  int v0 = lcnt[t*2], v1 = lcnt[t*2 + 1];
  part[t] = v0 + v1;
  __syncthreads();
  for (int off = 1; off < 256; off <<= 1) {
    int a = (t >= off) ? part[t - off] : 0;
    __syncthreads();
    part[t] += a;
    __syncthreads();
  }
  int pb = (t > 0) ? part[t - 1] : 0;
  loff[t*2] = pb;        lcur[t*2] = pb;
  loff[t*2+1] = pb + v0; lcur[t*2+1] = pb + v0;
  __syncthreads();
  for (int i = beg + t; i < end; i += 256) {
    int d = dst[i];
    int bk = d >> 8;
    int p = atomicAdd(&lcur[bk], 1);
    if (p < FB_CAP) sbuf[p] = (uint32)src[i] | ((uint32)(d & 255) << 20);
  }
  __syncthreads();
  for (int bk = t; bk < B_; bk += 256) {
    int c = lcnt[bk];
    gbase[bk] = c ? atomicAdd(&gcursor[bk], c) : 0;
  }
  __syncthreads();
  int grp = t >> 4, gl = t & 15;     // 16 groups of 16 lanes
  for (int bk = grp; bk < B_; bk += 16) {
    int c = lcnt[bk];
    int gb = gbase[bk];
    int lo = loff[bk];
    for (int i = gl; i < c; i += 16)
      pairs[gb + i] = sbuf[lo + i];
  }
}

// ---- per-bucket counting sort -> CSR (512 threads, LDS-staged pairs)
__global__ __launch_bounds__(512) void k_bsort(const uint32* __restrict__ pairs,
                        const int* __restrict__ boff, int* __restrict__ row_ptr,
                        int* __restrict__ eidx, int N_) {
  __shared__ uint32 sb[BS_CAP];
  __shared__ int cnt[256];
  __shared__ int scan[256];
  __shared__ int cursor[256];
  int t = threadIdx.x, b = blockIdx.x;
  if (t < 256) cnt[t] = 0;
  __syncthreads();
  int beg = boff[b], end = boff[b + 1];
  int n = end - beg;
  for (int i = t; i < n; i += 512) {
    uint32 pk = pairs[beg + i];
    if (i < BS_CAP) sb[i] = pk;
    atomicAdd(&cnt[pk >> 20], 1);
  }
  __syncthreads();
  int v = (t < 256) ? cnt[t] : 0;
  if (t < 256) scan[t] = v;
  __syncthreads();
  for (int off = 1; off < 256; off <<= 1) {
    int a = (t >= off && t < 256) ? scan[t - off] : 0;
    __syncthreads();
    if (t < 256) scan[t] += a;
    __syncthreads();
  }
  if (t < 256) {
    int ex = scan[t] - v;
    cursor[t] = ex;
    int node = b * NPB + t;
    if (node < N_) row_ptr[node] = beg + ex;
  }
  __syncthreads();
  for (int i = t; i < n; i += 512) {
    uint32 pk = (i < BS_CAP) ? sb[i] : pairs[beg + i];
    int j = pk >> 20;
    int p = atomicAdd(&cursor[j], 1);
    eidx[beg + p] = (int)(pk & 0xFFFFF);
  }
}

// ---- one wave per node over [n0,n1), 4-deep MLP, nontemporal index loads
__global__ __launch_bounds__(256) void k_gather(const uint32* __restrict__ hb,
                        const int* __restrict__ row_ptr, const int* __restrict__ eidx,
                        const float* __restrict__ eps1, uint32* __restrict__ gb,
                        int n0, int n1) {
  int w = n0 + (int)((blockIdx.x*blockDim.x + threadIdx.x) >> 6);
  w = __builtin_amdgcn_readfirstlane(w);
  int lane = threadIdx.x & 63;
  if (w >= n1) return;
  int beg = __builtin_nontemporal_load(row_ptr + w);
  int end = __builtin_nontemporal_load(row_ptr + w + 1);
  float2 a0 = {0.f,0.f}, a1 = {0.f,0.f}, a2 = {0.f,0.f}, a3 = {0.f,0.f};
  int e = beg;
  for (; e + 3 < end; e += 4) {
    int s0 = __builtin_nontemporal_load(eidx + e);
    int s1 = __builtin_nontemporal_load(eidx + e + 1);
    int s2 = __builtin_nontemporal_load(eidx + e + 2);
    int s3 = __builtin_nontemporal_load(eidx + e + 3);
    uint32 u0 = hb[(size_t)s0*64 + lane];
    uint32 u1 = hb[(size_t)s1*64 + lane];
    uint32 u2 = hb[(size_t)s2*64 + lane];
    uint32 u3 = hb[(size_t)s3*64 + lane];
    a0.x += bflo(u0); a0.y += bfhi(u0);
    a1.x += bflo(u1); a1.y += bfhi(u1);
    a2.x += bflo(u2); a2.y += bfhi(u2);
    a3.x += bflo(u3); a3.y += bfhi(u3);
  }
  for (; e < end; e++) {
    int s0 = __builtin_nontemporal_load(eidx + e);
    uint32 u0 = hb[(size_t)s0*64 + lane];
    a0.x += bflo(u0); a0.y += bfhi(u0);
  }
  float degf = (float)(end - beg);
  float e1 = eps1[0];
  uint32 hu = hb[(size_t)w*64 + lane];
  float ox = ((a0.x + a1.x) + (a2.x + a3.x)) / degf + e1 * bflo(hu);
  float oy = ((a0.y + a1.y) + (a2.y + a3.y)) / degf + e1 * bfhi(hu);
  gb[(size_t)w*64 + lane] = f2bf(ox) | (f2bf(oy) << 16);
}

// ---- y = g@W1^T via MFMA, reduced in-register to per-block col sum/sumsq
__global__ __launch_bounds__(256) void k_xstat(const uint32* __restrict__ gb,
                     const ushort* __restrict__ W1b, float* __restrict__ yslab, int N_) {
  __shared__ float wsl[4][512];
  int t = threadIdx.x;
  int l = t & 63, w = t >> 6;
  int m0 = blockIdx.x*64 + w*16;
  int lm = l & 15, lq = l >> 4;
  const uint4* gb4 = (const uint4*)gb;
  const uint4* W4  = (const uint4*)W1b;
  int arow = m0 + lm; if (arow > N_-1) arow = N_-1;
  U16B a[4];
  #pragma unroll
  for (int kc=0; kc<4; kc++) a[kc].u = gb4[(size_t)arow*16 + kc*4 + lq];
  f32x4 acc[16];
  #pragma unroll
  for (int nt=0; nt<16; nt++) acc[nt] = (f32x4)0.f;
  #pragma unroll
  for (int nt=0; nt<16; nt++){
    int nrow = nt*16 + lm;
    #pragma unroll
    for (int kc=0; kc<4; kc++){
      U16B b; b.u = W4[(size_t)nrow*16 + kc*4 + lq];
      acc[nt] = __builtin_amdgcn_mfma_f32_16x16x32_bf16(a[kc].s, b.s, acc[nt], 0, 0, 0);
    }
  }
  #pragma unroll
  for (int nt=0; nt<16; nt++){
    float s4 = 0.f, q4 = 0.f;
    #pragma unroll
    for (int r=0; r<4; r++){
      int row = m0 + lq*4 + r;
      if (row < N_) { float v = acc[nt][r]; s4 += v; q4 += v*v; }
    }
    s4 += __shfl_xor(s4, 16, 64); s4 += __shfl_xor(s4, 32, 64);
    q4 += __shfl_xor(q4, 16, 64); q4 += __shfl_xor(q4, 32, 64);
    if (lq == 0) { wsl[w][nt*16+lm] = s4; wsl[w][256+nt*16+lm] = q4; }
  }
  __syncthreads();
  float o0 = wsl[0][t] + wsl[1][t] + wsl[2][t] + wsl[3][t];
  float o1 = wsl[0][256+t] + wsl[1][256+t] + wsl[2][256+t] + wsl[3][256+t];
  yslab[(size_t)blockIdx.x*512 + t] = o0;
  yslab[(size_t)blockIdx.x*512 + 256 + t] = o1;
}

// ---- reduce yslab[nblk][512] -> ysum2[YG][512] (non-atomic partials)
__global__ __launch_bounds__(256) void k_yreduce(const float* __restrict__ yslab,
                        float* __restrict__ ysum2, int nblk, int per) {
  int i = blockIdx.x*256 + threadIdx.x;
  if (i >= 512) return;
  int g2 = blockIdx.y;
  int k0 = g2 * per;
  int k1 = min(k0 + per, nblk);
  float s = 0.f;
  for (int k = k0; k < k1; k++) s += yslab[(size_t)k*512 + i];
  ysum2[(size_t)g2*512 + i] = s;
}

// ---- fused stats + M build: block k -> Mb[k,:] (bf16) and cbuf[k]
__global__ __launch_bounds__(256) void k_smm(const float* __restrict__ ysum2,
                        const float* __restrict__ W1, const float* __restrict__ W2,
                        const float* __restrict__ b2, const float* __restrict__ gamma,
                        const float* __restrict__ beta, ushort* __restrict__ Mb,
                        float* __restrict__ cbuf, int N_) {
  __shared__ float sS[256];
  __shared__ float ws[256];
  __shared__ float red[256];
  int k = blockIdx.x, t = threadIdx.x;
  float s0 = 0.f, s1 = 0.f;
  #pragma unroll
  for (int g2 = 0; g2 < YG; g2++){
    s0 += ysum2[(size_t)g2*512 + t];
    s1 += ysum2[(size_t)g2*512 + 256 + t];
  }
  float invN = 1.f/(float)N_;
  float mean = s0*invN;
  float var = s1*invN - mean*mean;
  float sc = gamma[t]*rsqrtf(var + 1e-5f);
  float tt = beta[t] - mean*sc;
  float w2 = W2[(size_t)k*256 + t];
  sS[t] = sc;
  ws[t] = sc*w2;
  red[t] = tt*w2;
  __syncthreads();
  for (int off=128; off>0; off>>=1){
    if (t < off) red[t] += red[t+off];
    __syncthreads();
  }
  if (t == 0) cbuf[k] = b2[k] + red[0];
  if (t < 128){
    float acc = 0.f;
    for (int j=0;j<256;j++) acc += ws[j]*W1[(size_t)j*128 + t];
    Mb[(size_t)k*128 + t] = (ushort)f2bf(acc);
  }
}

// ---- out[i,k] = g[i,:].M[k,:] + c[k]  (R15 epilogue; rows [n0,n1))
__global__ __launch_bounds__(256) void k_out(const uint32* __restrict__ gb,
                     const ushort* __restrict__ Mb, const float* __restrict__ cb,
                     float* __restrict__ out, int n0, int n1) {
  __shared__ float st[4][16][132];
  int t = threadIdx.x;
  int l = t & 63, w = t >> 6;
  int m0 = n0 + blockIdx.x*64 + w*16;
  int lm = l & 15, lq = l >> 4;
  const uint4* gb4 = (const uint4*)gb;
  const uint4* Mb4 = (const uint4*)Mb;
  int arow = m0 + lm; if (arow > n1-1) arow = n1-1;
  U16B a[4];
  #pragma unroll
  for (int kc=0; kc<4; kc++) a[kc].u = gb4[(size_t)arow*16 + kc*4 + lq];
  f32x4 acc[16];
  #pragma unroll
  for (int nt=0; nt<16; nt++) acc[nt] = (f32x4)0.f;
  #pragma unroll
  for (int nt=0; nt<16; nt++){
    int nrow = nt*16 + lm;
    #pragma unroll
    for (int kc=0; kc<4; kc++){
      U16B b; b.u = Mb4[(size_t)nrow*16 + kc*4 + lq];
      acc[nt] = __builtin_amdgcn_mfma_f32_16x16x32_bf16(a[kc].s, b.s, acc[nt], 0, 0, 0);
    }
  }
  int rr = l >> 5, cc = l & 31;
  #pragma unroll
  for (int half=0; half<2; half++){
    #pragma unroll
    for (int q8=0; q8<8; q8++){
      int nt = half*8 + q8;
      float cv = cb[nt*16 + lm];
      #pragma unroll
      for (int r=0; r<4; r++)
        st[w][lq*4+r][q8*16+lm] = acc[nt][r] + cv;
    }
    #pragma unroll
    for (int it=0; it<8; it++){
      int row = it*2 + rr;
      int gr = m0 + row;
      float4 v = *(float4*)&st[w][row][cc*4];
      if (gr < n1) *(float4*)&out[(size_t)gr*256 + half*128 + cc*4] = v;
    }
  }
}

extern "C" void kernel_launch(void* const* d_in, const int* in_sizes, int n_in,
                              void* d_out, int out_size, void* d_ws, size_t ws_size,
                              hipStream_t stream) {
  const float* h     = (const float*)d_in[0];
  const int*   esrc  = (const int*)d_in[1];
  const int*   edst  = (const int*)d_in[2];
  const float* W1    = (const float*)d_in[3];
  const float* b1    = (const float*)d_in[4];  (void)b1;
  const float* W2    = (const float*)d_in[5];
  const float* b2    = (const float*)d_in[6];
  const float* gamma = (const float*)d_in[7];
  const float* beta  = (const float*)d_in[8];
  const float* eps1  = (const float*)d_in[9];
  int N = in_sizes[0] / IN_DIM;
  int E = in_sizes[1];
  int B = (N + NPB - 1) / NPB;          // 391 for N=100000
  int nxb = (N + 63) / 64;
  float* out = (float*)d_out;

  char* ws = (char*)d_ws;
  size_t off = 0;
  auto alloc = [&](size_t bytes)->char* {
    char* p = ws + off; off = align256(off + bytes); return p;
  };
  int*    gcount  = (int*)   alloc((size_t)B*4);
  int*    boff    = (int*)   alloc(((size_t)B+1)*4);
  int*    gcursor = (int*)   alloc((size_t)B*4);
  int*    row_ptr = (int*)   alloc(((size_t)N+1)*4);
  uint32* pairs   = (uint32*)alloc((size_t)E*4);
  int*    eidx    = (int*)   alloc((size_t)E*4);
  uint32* hb      = (uint32*)alloc((size_t)N*64*4);
  uint32* gb      = (uint32*)alloc((size_t)N*64*4);
  uint32* W1b     = (uint32*)alloc(256*128*2);
  float*  ysum2   = (float*) alloc((size_t)YG*512*4);
  float*  yslab   = (float*) alloc((size_t)nxb*512*4);
  float*  sbuf    = (float*) alloc(256*4);  (void)sbuf;
  float*  cbuf    = (float*) alloc(256*4);
  ushort* Mb      = (ushort*)alloc(256*128*2);
  (void)n_in; (void)out_size; (void)ws_size;

  hipMemsetAsync(gcount, 0, (size_t)B*4, stream);

  k_prep  <<<1024, 256, 0, stream>>>(h, hb, N*IN_DIM/4, W1, W1b, edst, gcount, E, B);
  k_bscan <<<1, 256, 0, stream>>>(gcount, boff, gcursor, row_ptr, B, N);
  {
    int fbblk = (E + FB_CAP - 101) / (FB_CAP - 100);
    if (fbblk < 512) fbblk = 512;
    k_bfill<<<fbblk, 256, 0, stream>>>(esrc, edst, gcursor, pairs, E, B);
  }
  k_bsort <<<B, 512, 0, stream>>>(pairs, boff, row_ptr, eidx, N);
  {
    int nh = N / 2;
    k_gather<<<(nh+3)/4, 256, 0, stream>>>(hb, row_ptr, eidx, eps1, gb, 0, nh);
    k_gather<<<((N-nh)+3)/4, 256, 0, stream>>>(hb, row_ptr, eidx, eps1, gb, nh, N);
  }
  k_xstat <<<nxb, 256, 0, stream>>>(gb, (const ushort*)W1b, yslab, N);
  {
    int per = (nxb + YG - 1) / YG;
    dim3 rgrid(2, YG);
    k_yreduce<<<rgrid, 256, 0, stream>>>(yslab, ysum2, nxb, per);
  }
  k_smm   <<<256, 256, 0, stream>>>(ysum2, W1, W2, b2, gamma, beta, Mb, cbuf, N);
  {
    int nh = N / 2;
    int nh2 = N - nh;
    k_out<<<(nh+63)/64, 256, 0, stream>>>(gb, Mb, cbuf, out, 0, nh);
    k_out<<<(nh2+63)/64, 256, 0, stream>>>(gb, Mb, cbuf, out, nh, N);
  }
}

// Round 19
// 386.093 us; speedup vs baseline: 1.0099x; 1.0099x over previous
//
#include <hip/hip_runtime.h>
#include <cstdint>
#include <cstddef>

// Extractor_N2V folded: g = seg_sum(h[src],dst)/deg + eps1*h  (bf16 storage)
// BN stats via y = g@W1^T MFMA pass reduced to per-channel sum/sumsq;
// out = g @ M^T + c with M = W2 diag(s) W1 (bf16). CSR via bucket sort.
// R19: hipMemsetAsync(gcount) -> k_zero kernel (the 58us fillBufferAligned
// was ours); k_xstat acc halved (32 VGPR acc, below the 64-VGPR occupancy
// cliff).

#define IN_DIM 128
#define H_DIM 256
#define NPB 256
#define MAXB 1792
#define FB_CAP 6400
#define BS_CAP 10240
#define YG 16

typedef unsigned int uint32;
typedef unsigned short ushort;
typedef __attribute__((ext_vector_type(8))) short short8;
typedef __attribute__((ext_vector_type(4))) float f32x4;
typedef __attribute__((ext_vector_type(4))) uint32 u32x4;

union U16B { uint4 u; short8 s; };

static inline size_t align256(size_t x){ return (x + 255) & ~(size_t)255; }

__device__ inline uint32 f2bf(float f){
  uint32 u = __float_as_uint(f);
  return (u + 0x7FFFu + ((u >> 16) & 1u)) >> 16;   // RNE
}
__device__ inline float bflo(uint32 u){ return __uint_as_float(u << 16); }
__device__ inline float bfhi(uint32 u){ return __uint_as_float(u & 0xFFFF0000u); }

// ---- zero gcount (replaces pathological 58us runtime fillBuffer)
__global__ __launch_bounds__(256) void k_zero(int* __restrict__ g, int n) {
  int i = blockIdx.x*256 + threadIdx.x;
  if (i < n) g[i] = 0;
}

// ---- fused: h->hb (bf16), W1->W1b (bf16), bucket histogram (dst>>8)
__global__ __launch_bounds__(256) void k_prep(const float* __restrict__ h,
                        uint32* __restrict__ hb2, int n4,
                        const float* __restrict__ W1, uint32* __restrict__ W1b2,
                        const int* __restrict__ dst, int* __restrict__ gcount,
                        int E_, int B_) {
  __shared__ int lc[512];
  int t = threadIdx.x;
  int stride = gridDim.x*256;
  for (int i = blockIdx.x*256 + t; i < n4; i += stride) {
    u32x4 uv = __builtin_nontemporal_load((const u32x4*)h + i);
    uint32 lo = f2bf(__uint_as_float(uv.x)) | (f2bf(__uint_as_float(uv.y)) << 16);
    uint32 hi = f2bf(__uint_as_float(uv.z)) | (f2bf(__uint_as_float(uv.w)) << 16);
    ((uint2*)hb2)[i] = make_uint2(lo, hi);
  }
  for (int i = blockIdx.x*256 + t; i < 256*128/4; i += stride) {
    u32x4 uv = *((const u32x4*)W1 + i);
    uint32 lo = f2bf(__uint_as_float(uv.x)) | (f2bf(__uint_as_float(uv.y)) << 16);
    uint32 hi = f2bf(__uint_as_float(uv.z)) | (f2bf(__uint_as_float(uv.w)) << 16);
    ((uint2*)W1b2)[i] = make_uint2(lo, hi);
  }
  for (int j = t; j < B_; j += 256) lc[j] = 0;
  __syncthreads();
  int per = (E_ + gridDim.x - 1) / gridDim.x;
  int beg = blockIdx.x * per, end = min(beg + per, E_);
  for (int j = beg + t; j < end; j += 256)
    atomicAdd(&lc[__builtin_nontemporal_load(dst + j) >> 8], 1);
  __syncthreads();
  for (int j = t; j < B_; j += 256) { int v = lc[j]; if (v) atomicAdd(&gcount[j], v); }
}

// ---- exclusive scan of bucket counts
__global__ __launch_bounds__(256) void k_bscan(const int* __restrict__ gcount,
                        int* __restrict__ boff, int* __restrict__ gcursor,
                        int* __restrict__ row_ptr, int B_, int N_) {
  __shared__ int part[256];
  __shared__ int vals[MAXB];
  int t = threadIdx.x;
  int base = t * 7;
  int s = 0;
  #pragma unroll
  for (int k = 0; k < 7; k++) {
    int idx = base + k;
    int v = (idx < B_) ? gcount[idx] : 0;
    vals[idx < MAXB ? idx : MAXB-1] = s;
    s += v;
  }
  part[t] = s;
  __syncthreads();
  for (int off = 1; off < 256; off <<= 1) {
    int a = (t >= off) ? part[t - off] : 0;
    __syncthreads();
    part[t] += a;
    __syncthreads();
  }
  int pbase = (t > 0) ? part[t - 1] : 0;
  #pragma unroll
  for (int k = 0; k < 7; k++) {
    int idx = base + k;
    if (idx < B_) { int o = pbase + vals[idx]; boff[idx] = o; gcursor[idx] = o; }
  }
  if (t == 255) { boff[B_] = part[255]; row_ptr[N_] = part[255]; }
}

// ---- LDS counting-sort scatter: local sort, reserve chunk, burst chunk copy
__global__ __launch_bounds__(256) void k_bfill(const int* __restrict__ src,
                        const int* __restrict__ dst, int* __restrict__ gcursor,
                        uint32* __restrict__ pairs, int E_, int B_) {
  __shared__ uint32 sbuf[FB_CAP];
  __shared__ int lcnt[512];
  __shared__ int loff[512];
  __shared__ int lcur[512];
  __shared__ int gbase[512];
  __shared__ int part[256];
  int t = threadIdx.x;
  for (int i = t; i < 512; i += 256) lcnt[i] = 0;
  __syncthreads();
  int per = (E_ + gridDim.x - 1) / gridDim.x;
  int beg = blockIdx.x * per, end = min(beg + per, E_);
  for (int i = beg + t; i < end; i += 256)
    atomicAdd(&lcnt[__builtin_nontemporal_load(dst + i) >> 8], 1);
  __syncthreads();
  int v0 = lcnt[t*2], v1 = lcnt[t*2 + 1];
  part[t] = v0 + v1;
  __syncthreads();
  for (int off = 1; off < 256; off <<= 1) {
    int a = (t >= off) ? part[t - off] : 0;
    __syncthreads();
    part[t] += a;
    __syncthreads();
  }
  int pb = (t > 0) ? part[t - 1] : 0;
  loff[t*2] = pb;        lcur[t*2] = pb;
  loff[t*2+1] = pb + v0; lcur[t*2+1] = pb + v0;
  __syncthreads();
  for (int i = beg + t; i < end; i += 256) {
    int d = dst[i];
    int bk = d >> 8;
    int p = atomicAdd(&lcur[bk], 1);
    if (p < FB_CAP) sbuf[p] = (uint32)src[i] | ((uint32)(d & 255) << 20);
  }
  __syncthreads();
  for (int bk = t; bk < B_; bk += 256) {
    int c = lcnt[bk];
    gbase[bk] = c ? atomicAdd(&gcursor[bk], c) : 0;
  }
  __syncthreads();
  int grp = t >> 4, gl = t & 15;
  for (int bk = grp; bk < B_; bk += 16) {
    int c = lcnt[bk];
    int gb = gbase[bk];
    int lo = loff[bk];
    for (int i = gl; i < c; i += 16)
      pairs[gb + i] = sbuf[lo + i];
  }
}

// ---- per-bucket counting sort -> CSR (512 threads, LDS-staged pairs)
__global__ __launch_bounds__(512) void k_bsort(const uint32* __restrict__ pairs,
                        const int* __restrict__ boff, int* __restrict__ row_ptr,
                        int* __restrict__ eidx, int N_) {
  __shared__ uint32 sb[BS_CAP];
  __shared__ int cnt[256];
  __shared__ int scan[256];
  __shared__ int cursor[256];
  int t = threadIdx.x, b = blockIdx.x;
  if (t < 256) cnt[t] = 0;
  __syncthreads();
  int beg = boff[b], end = boff[b + 1];
  int n = end - beg;
  for (int i = t; i < n; i += 512) {
    uint32 pk = pairs[beg + i];
    if (i < BS_CAP) sb[i] = pk;
    atomicAdd(&cnt[pk >> 20], 1);
  }
  __syncthreads();
  int v = (t < 256) ? cnt[t] : 0;
  if (t < 256) scan[t] = v;
  __syncthreads();
  for (int off = 1; off < 256; off <<= 1) {
    int a = (t >= off && t < 256) ? scan[t - off] : 0;
    __syncthreads();
    if (t < 256) scan[t] += a;
    __syncthreads();
  }
  if (t < 256) {
    int ex = scan[t] - v;
    cursor[t] = ex;
    int node = b * NPB + t;
    if (node < N_) row_ptr[node] = beg + ex;
  }
  __syncthreads();
  for (int i = t; i < n; i += 512) {
    uint32 pk = (i < BS_CAP) ? sb[i] : pairs[beg + i];
    int j = pk >> 20;
    int p = atomicAdd(&cursor[j], 1);
    eidx[beg + p] = (int)(pk & 0xFFFFF);
  }
}

// ---- one wave per node over [n0,n1), 4-deep MLP, nontemporal index loads
__global__ __launch_bounds__(256) void k_gather(const uint32* __restrict__ hb,
                        const int* __restrict__ row_ptr, const int* __restrict__ eidx,
                        const float* __restrict__ eps1, uint32* __restrict__ gb,
                        int n0, int n1) {
  int w = n0 + (int)((blockIdx.x*blockDim.x + threadIdx.x) >> 6);
  w = __builtin_amdgcn_readfirstlane(w);
  int lane = threadIdx.x & 63;
  if (w >= n1) return;
  int beg = __builtin_nontemporal_load(row_ptr + w);
  int end = __builtin_nontemporal_load(row_ptr + w + 1);
  float2 a0 = {0.f,0.f}, a1 = {0.f,0.f}, a2 = {0.f,0.f}, a3 = {0.f,0.f};
  int e = beg;
  for (; e + 3 < end; e += 4) {
    int s0 = __builtin_nontemporal_load(eidx + e);
    int s1 = __builtin_nontemporal_load(eidx + e + 1);
    int s2 = __builtin_nontemporal_load(eidx + e + 2);
    int s3 = __builtin_nontemporal_load(eidx + e + 3);
    uint32 u0 = hb[(size_t)s0*64 + lane];
    uint32 u1 = hb[(size_t)s1*64 + lane];
    uint32 u2 = hb[(size_t)s2*64 + lane];
    uint32 u3 = hb[(size_t)s3*64 + lane];
    a0.x += bflo(u0); a0.y += bfhi(u0);
    a1.x += bflo(u1); a1.y += bfhi(u1);
    a2.x += bflo(u2); a2.y += bfhi(u2);
    a3.x += bflo(u3); a3.y += bfhi(u3);
  }
  for (; e < end; e++) {
    int s0 = __builtin_nontemporal_load(eidx + e);
    uint32 u0 = hb[(size_t)s0*64 + lane];
    a0.x += bflo(u0); a0.y += bfhi(u0);
  }
  float degf = (float)(end - beg);
  float e1 = eps1[0];
  uint32 hu = hb[(size_t)w*64 + lane];
  float ox = ((a0.x + a1.x) + (a2.x + a3.x)) / degf + e1 * bflo(hu);
  float oy = ((a0.y + a1.y) + (a2.y + a3.y)) / degf + e1 * bfhi(hu);
  gb[(size_t)w*64 + lane] = f2bf(ox) | (f2bf(oy) << 16);
}

// ---- y = g@W1^T via MFMA -> per-block col sum/sumsq. acc halved (32 VGPR)
__global__ __launch_bounds__(256) void k_xstat(const uint32* __restrict__ gb,
                     const ushort* __restrict__ W1b, float* __restrict__ yslab, int N_) {
  __shared__ float wsl[4][512];
  int t = threadIdx.x;
  int l = t & 63, w = t >> 6;
  int m0 = blockIdx.x*64 + w*16;
  int lm = l & 15, lq = l >> 4;
  const uint4* gb4 = (const uint4*)gb;
  const uint4* W4  = (const uint4*)W1b;
  int arow = m0 + lm; if (arow > N_-1) arow = N_-1;
  U16B a[4];
  #pragma unroll
  for (int kc=0; kc<4; kc++) a[kc].u = gb4[(size_t)arow*16 + kc*4 + lq];
  #pragma unroll
  for (int half=0; half<2; half++){
    f32x4 acc[8];
    #pragma unroll
    for (int j=0; j<8; j++) acc[j] = (f32x4)0.f;
    #pragma unroll
    for (int j=0; j<8; j++){
      int nrow = (half*8 + j)*16 + lm;
      #pragma unroll
      for (int kc=0; kc<4; kc++){
        U16B b; b.u = W4[(size_t)nrow*16 + kc*4 + lq];
        acc[j] = __builtin_amdgcn_mfma_f32_16x16x32_bf16(a[kc].s, b.s, acc[j], 0, 0, 0);
      }
    }
    #pragma unroll
    for (int j=0; j<8; j++){
      int nt = half*8 + j;
      float s4 = 0.f, q4 = 0.f;
      #pragma unroll
      for (int r=0; r<4; r++){
        int row = m0 + lq*4 + r;
        if (row < N_) { float v = acc[j][r]; s4 += v; q4 += v*v; }
      }
      s4 += __shfl_xor(s4, 16, 64); s4 += __shfl_xor(s4, 32, 64);
      q4 += __shfl_xor(q4, 16, 64); q4 += __shfl_xor(q4, 32, 64);
      if (lq == 0) { wsl[w][nt*16+lm] = s4; wsl[w][256+nt*16+lm] = q4; }
    }
  }
  __syncthreads();
  float o0 = wsl[0][t] + wsl[1][t] + wsl[2][t] + wsl[3][t];
  float o1 = wsl[0][256+t] + wsl[1][256+t] + wsl[2][256+t] + wsl[3][256+t];
  yslab[(size_t)blockIdx.x*512 + t] = o0;
  yslab[(size_t)blockIdx.x*512 + 256 + t] = o1;
}

// ---- reduce yslab[nblk][512] -> ysum2[YG][512] (non-atomic partials)
__global__ __launch_bounds__(256) void k_yreduce(const float* __restrict__ yslab,
                        float* __restrict__ ysum2, int nblk, int per) {
  int i = blockIdx.x*256 + threadIdx.x;
  if (i >= 512) return;
  int g2 = blockIdx.y;
  int k0 = g2 * per;
  int k1 = min(k0 + per, nblk);
  float s = 0.f;
  for (int k = k0; k < k1; k++) s += yslab[(size_t)k*512 + i];
  ysum2[(size_t)g2*512 + i] = s;
}

// ---- fused stats + M build: block k -> Mb[k,:] (bf16) and cbuf[k]
__global__ __launch_bounds__(256) void k_smm(const float* __restrict__ ysum2,
                        const float* __restrict__ W1, const float* __restrict__ W2,
                        const float* __restrict__ b2, const float* __restrict__ gamma,
                        const float* __restrict__ beta, ushort* __restrict__ Mb,
                        float* __restrict__ cbuf, int N_) {
  __shared__ float ws[256];
  __shared__ float red[256];
  int k = blockIdx.x, t = threadIdx.x;
  float s0 = 0.f, s1 = 0.f;
  #pragma unroll
  for (int g2 = 0; g2 < YG; g2++){
    s0 += ysum2[(size_t)g2*512 + t];
    s1 += ysum2[(size_t)g2*512 + 256 + t];
  }
  float invN = 1.f/(float)N_;
  float mean = s0*invN;
  float var = s1*invN - mean*mean;
  float sc = gamma[t]*rsqrtf(var + 1e-5f);
  float tt = beta[t] - mean*sc;
  float w2 = W2[(size_t)k*256 + t];
  ws[t] = sc*w2;
  red[t] = tt*w2;
  __syncthreads();
  for (int off=128; off>0; off>>=1){
    if (t < off) red[t] += red[t+off];
    __syncthreads();
  }
  if (t == 0) cbuf[k] = b2[k] + red[0];
  if (t < 128){
    float acc = 0.f;
    for (int j=0;j<256;j++) acc += ws[j]*W1[(size_t)j*128 + t];
    Mb[(size_t)k*128 + t] = (ushort)f2bf(acc);
  }
}

// ---- out[i,k] = g[i,:].M[k,:] + c[k]  (R15 epilogue; rows [n0,n1))
__global__ __launch_bounds__(256) void k_out(const uint32* __restrict__ gb,
                     const ushort* __restrict__ Mb, const float* __restrict__ cb,
                     float* __restrict__ out, int n0, int n1) {
  __shared__ float st[4][16][132];
  int t = threadIdx.x;
  int l = t & 63, w = t >> 6;
  int m0 = n0 + blockIdx.x*64 + w*16;
  int lm = l & 15, lq = l >> 4;
  const uint4* gb4 = (const uint4*)gb;
  const uint4* Mb4 = (const uint4*)Mb;
  int arow = m0 + lm; if (arow > n1-1) arow = n1-1;
  U16B a[4];
  #pragma unroll
  for (int kc=0; kc<4; kc++) a[kc].u = gb4[(size_t)arow*16 + kc*4 + lq];
  f32x4 acc[16];
  #pragma unroll
  for (int nt=0; nt<16; nt++) acc[nt] = (f32x4)0.f;
  #pragma unroll
  for (int nt=0; nt<16; nt++){
    int nrow = nt*16 + lm;
    #pragma unroll
    for (int kc=0; kc<4; kc++){
      U16B b; b.u = Mb4[(size_t)nrow*16 + kc*4 + lq];
      acc[nt] = __builtin_amdgcn_mfma_f32_16x16x32_bf16(a[kc].s, b.s, acc[nt], 0, 0, 0);
    }
  }
  int rr = l >> 5, cc = l & 31;
  #pragma unroll
  for (int half=0; half<2; half++){
    #pragma unroll
    for (int q8=0; q8<8; q8++){
      int nt = half*8 + q8;
      float cv = cb[nt*16 + lm];
      #pragma unroll
      for (int r=0; r<4; r++)
        st[w][lq*4+r][q8*16+lm] = acc[nt][r] + cv;
    }
    #pragma unroll
    for (int it=0; it<8; it++){
      int row = it*2 + rr;
      int gr = m0 + row;
      float4 v = *(float4*)&st[w][row][cc*4];
      if (gr < n1) *(float4*)&out[(size_t)gr*256 + half*128 + cc*4] = v;
    }
  }
}

extern "C" void kernel_launch(void* const* d_in, const int* in_sizes, int n_in,
                              void* d_out, int out_size, void* d_ws, size_t ws_size,
                              hipStream_t stream) {
  const float* h     = (const float*)d_in[0];
  const int*   esrc  = (const int*)d_in[1];
  const int*   edst  = (const int*)d_in[2];
  const float* W1    = (const float*)d_in[3];
  const float* b1    = (const float*)d_in[4];  (void)b1;
  const float* W2    = (const float*)d_in[5];
  const float* b2    = (const float*)d_in[6];
  const float* gamma = (const float*)d_in[7];
  const float* beta  = (const float*)d_in[8];
  const float* eps1  = (const float*)d_in[9];
  int N = in_sizes[0] / IN_DIM;
  int E = in_sizes[1];
  int B = (N + NPB - 1) / NPB;          // 391 for N=100000
  int nxb = (N + 63) / 64;
  float* out = (float*)d_out;

  char* ws = (char*)d_ws;
  size_t off = 0;
  auto alloc = [&](size_t bytes)->char* {
    char* p = ws + off; off = align256(off + bytes); return p;
  };
  int*    gcount  = (int*)   alloc((size_t)B*4);
  int*    boff    = (int*)   alloc(((size_t)B+1)*4);
  int*    gcursor = (int*)   alloc((size_t)B*4);
  int*    row_ptr = (int*)   alloc(((size_t)N+1)*4);
  uint32* pairs   = (uint32*)alloc((size_t)E*4);
  int*    eidx    = (int*)   alloc((size_t)E*4);
  uint32* hb      = (uint32*)alloc((size_t)N*64*4);
  uint32* gb      = (uint32*)alloc((size_t)N*64*4);
  uint32* W1b     = (uint32*)alloc(256*128*2);
  float*  ysum2   = (float*) alloc((size_t)YG*512*4);
  float*  yslab   = (float*) alloc((size_t)nxb*512*4);
  float*  cbuf    = (float*) alloc(256*4);
  ushort* Mb      = (ushort*)alloc(256*128*2);
  (void)n_in; (void)out_size; (void)ws_size;

  k_zero  <<<(B+255)/256, 256, 0, stream>>>(gcount, B);
  k_prep  <<<1024, 256, 0, stream>>>(h, hb, N*IN_DIM/4, W1, W1b, edst, gcount, E, B);
  k_bscan <<<1, 256, 0, stream>>>(gcount, boff, gcursor, row_ptr, B, N);
  {
    int fbblk = (E + FB_CAP - 101) / (FB_CAP - 100);
    if (fbblk < 512) fbblk = 512;
    k_bfill<<<fbblk, 256, 0, stream>>>(esrc, edst, gcursor, pairs, E, B);
  }
  k_bsort <<<B, 512, 0, stream>>>(pairs, boff, row_ptr, eidx, N);
  {
    int nh = N / 2;
    k_gather<<<(nh+3)/4, 256, 0, stream>>>(hb, row_ptr, eidx, eps1, gb, 0, nh);
    k_gather<<<((N-nh)+3)/4, 256, 0, stream>>>(hb, row_ptr, eidx, eps1, gb, nh, N);
  }
  k_xstat <<<nxb, 256, 0, stream>>>(gb, (const ushort*)W1b, yslab, N);
  {
    int per = (nxb + YG - 1) / YG;
    dim3 rgrid(2, YG);
    k_yreduce<<<rgrid, 256, 0, stream>>>(yslab, ysum2, nxb, per);
  }
  k_smm   <<<256, 256, 0, stream>>>(ysum2, W1, W2, b2, gamma, beta, Mb, cbuf, N);
  {
    int nh = N / 2;
    int nh2 = N - nh;
    k_out<<<(nh+63)/64, 256, 0, stream>>>(gb, Mb, cbuf, out, 0, nh);
    k_out<<<(nh2+63)/64, 256, 0, stream>>>(gb, Mb, cbuf, out, nh, N);
  }
}

// Round 20
// 308.555 us; speedup vs baseline: 1.2637x; 1.2513x over previous
//
#include <hip/hip_runtime.h>
#include <cstdint>
#include <cstddef>

// Extractor_N2V folded: g = seg_sum(h[src],dst)/deg + eps1*h  (bf16 storage)
// BN stats via y = g@W1^T MFMA pass reduced to per-channel sum/sumsq;
// out = g @ M^T + c with M = W2 diag(s) W1 (bf16). CSR via bucket sort.
// R20: k_xstat/k_out stage the 64KB B-matrix in LDS (2x32KB halves, padded
// rows) instead of per-wave L2 streams; single gather/out launches.

#define IN_DIM 128
#define H_DIM 256
#define NPB 256
#define MAXB 1792
#define FB_CAP 6400
#define BS_CAP 10240
#define YG 16

typedef unsigned int uint32;
typedef unsigned short ushort;
typedef __attribute__((ext_vector_type(8))) short short8;
typedef __attribute__((ext_vector_type(4))) float f32x4;
typedef __attribute__((ext_vector_type(4))) uint32 u32x4;

union U16B { uint4 u; short8 s; };

static inline size_t align256(size_t x){ return (x + 255) & ~(size_t)255; }

__device__ inline uint32 f2bf(float f){
  uint32 u = __float_as_uint(f);
  return (u + 0x7FFFu + ((u >> 16) & 1u)) >> 16;   // RNE
}
__device__ inline float bflo(uint32 u){ return __uint_as_float(u << 16); }
__device__ inline float bfhi(uint32 u){ return __uint_as_float(u & 0xFFFF0000u); }

// ---- zero gcount
__global__ __launch_bounds__(256) void k_zero(int* __restrict__ g, int n) {
  int i = blockIdx.x*256 + threadIdx.x;
  if (i < n) g[i] = 0;
}

// ---- fused: h->hb (bf16), W1->W1b (bf16), bucket histogram (dst>>8)
__global__ __launch_bounds__(256) void k_prep(const float* __restrict__ h,
                        uint32* __restrict__ hb2, int n4,
                        const float* __restrict__ W1, uint32* __restrict__ W1b2,
                        const int* __restrict__ dst, int* __restrict__ gcount,
                        int E_, int B_) {
  __shared__ int lc[512];
  int t = threadIdx.x;
  int stride = gridDim.x*256;
  for (int i = blockIdx.x*256 + t; i < n4; i += stride) {
    u32x4 uv = __builtin_nontemporal_load((const u32x4*)h + i);
    uint32 lo = f2bf(__uint_as_float(uv.x)) | (f2bf(__uint_as_float(uv.y)) << 16);
    uint32 hi = f2bf(__uint_as_float(uv.z)) | (f2bf(__uint_as_float(uv.w)) << 16);
    ((uint2*)hb2)[i] = make_uint2(lo, hi);
  }
  for (int i = blockIdx.x*256 + t; i < 256*128/4; i += stride) {
    u32x4 uv = *((const u32x4*)W1 + i);
    uint32 lo = f2bf(__uint_as_float(uv.x)) | (f2bf(__uint_as_float(uv.y)) << 16);
    uint32 hi = f2bf(__uint_as_float(uv.z)) | (f2bf(__uint_as_float(uv.w)) << 16);
    ((uint2*)W1b2)[i] = make_uint2(lo, hi);
  }
  for (int j = t; j < B_; j += 256) lc[j] = 0;
  __syncthreads();
  int per = (E_ + gridDim.x - 1) / gridDim.x;
  int beg = blockIdx.x * per, end = min(beg + per, E_);
  for (int j = beg + t; j < end; j += 256)
    atomicAdd(&lc[__builtin_nontemporal_load(dst + j) >> 8], 1);
  __syncthreads();
  for (int j = t; j < B_; j += 256) { int v = lc[j]; if (v) atomicAdd(&gcount[j], v); }
}

// ---- exclusive scan of bucket counts
__global__ __launch_bounds__(256) void k_bscan(const int* __restrict__ gcount,
                        int* __restrict__ boff, int* __restrict__ gcursor,
                        int* __restrict__ row_ptr, int B_, int N_) {
  __shared__ int part[256];
  __shared__ int vals[MAXB];
  int t = threadIdx.x;
  int base = t * 7;
  int s = 0;
  #pragma unroll
  for (int k = 0; k < 7; k++) {
    int idx = base + k;
    int v = (idx < B_) ? gcount[idx] : 0;
    vals[idx < MAXB ? idx : MAXB-1] = s;
    s += v;
  }
  part[t] = s;
  __syncthreads();
  for (int off = 1; off < 256; off <<= 1) {
    int a = (t >= off) ? part[t - off] : 0;
    __syncthreads();
    part[t] += a;
    __syncthreads();
  }
  int pbase = (t > 0) ? part[t - 1] : 0;
  #pragma unroll
  for (int k = 0; k < 7; k++) {
    int idx = base + k;
    if (idx < B_) { int o = pbase + vals[idx]; boff[idx] = o; gcursor[idx] = o; }
  }
  if (t == 255) { boff[B_] = part[255]; row_ptr[N_] = part[255]; }
}

// ---- LDS counting-sort scatter: local sort, reserve chunk, burst chunk copy
__global__ __launch_bounds__(256) void k_bfill(const int* __restrict__ src,
                        const int* __restrict__ dst, int* __restrict__ gcursor,
                        uint32* __restrict__ pairs, int E_, int B_) {
  __shared__ uint32 sbuf[FB_CAP];
  __shared__ int lcnt[512];
  __shared__ int loff[512];
  __shared__ int lcur[512];
  __shared__ int gbase[512];
  __shared__ int part[256];
  int t = threadIdx.x;
  for (int i = t; i < 512; i += 256) lcnt[i] = 0;
  __syncthreads();
  int per = (E_ + gridDim.x - 1) / gridDim.x;
  int beg = blockIdx.x * per, end = min(beg + per, E_);
  for (int i = beg + t; i < end; i += 256)
    atomicAdd(&lcnt[__builtin_nontemporal_load(dst + i) >> 8], 1);
  __syncthreads();
  int v0 = lcnt[t*2], v1 = lcnt[t*2 + 1];
  part[t] = v0 + v1;
  __syncthreads();
  for (int off = 1; off < 256; off <<= 1) {
    int a = (t >= off) ? part[t - off] : 0;
    __syncthreads();
    part[t] += a;
    __syncthreads();
  }
  int pb = (t > 0) ? part[t - 1] : 0;
  loff[t*2] = pb;        lcur[t*2] = pb;
  loff[t*2+1] = pb + v0; lcur[t*2+1] = pb + v0;
  __syncthreads();
  for (int i = beg + t; i < end; i += 256) {
    int d = dst[i];
    int bk = d >> 8;
    int p = atomicAdd(&lcur[bk], 1);
    if (p < FB_CAP) sbuf[p] = (uint32)src[i] | ((uint32)(d & 255) << 20);
  }
  __syncthreads();
  for (int bk = t; bk < B_; bk += 256) {
    int c = lcnt[bk];
    gbase[bk] = c ? atomicAdd(&gcursor[bk], c) : 0;
  }
  __syncthreads();
  int grp = t >> 4, gl = t & 15;
  for (int bk = grp; bk < B_; bk += 16) {
    int c = lcnt[bk];
    int gb = gbase[bk];
    int lo = loff[bk];
    for (int i = gl; i < c; i += 16)
      pairs[gb + i] = sbuf[lo + i];
  }
}

// ---- per-bucket counting sort -> CSR (512 threads, LDS-staged pairs)
__global__ __launch_bounds__(512) void k_bsort(const uint32* __restrict__ pairs,
                        const int* __restrict__ boff, int* __restrict__ row_ptr,
                        int* __restrict__ eidx, int N_) {
  __shared__ uint32 sb[BS_CAP];
  __shared__ int cnt[256];
  __shared__ int scan[256];
  __shared__ int cursor[256];
  int t = threadIdx.x, b = blockIdx.x;
  if (t < 256) cnt[t] = 0;
  __syncthreads();
  int beg = boff[b], end = boff[b + 1];
  int n = end - beg;
  for (int i = t; i < n; i += 512) {
    uint32 pk = pairs[beg + i];
    if (i < BS_CAP) sb[i] = pk;
    atomicAdd(&cnt[pk >> 20], 1);
  }
  __syncthreads();
  int v = (t < 256) ? cnt[t] : 0;
  if (t < 256) scan[t] = v;
  __syncthreads();
  for (int off = 1; off < 256; off <<= 1) {
    int a = (t >= off && t < 256) ? scan[t - off] : 0;
    __syncthreads();
    if (t < 256) scan[t] += a;
    __syncthreads();
  }
  if (t < 256) {
    int ex = scan[t] - v;
    cursor[t] = ex;
    int node = b * NPB + t;
    if (node < N_) row_ptr[node] = beg + ex;
  }
  __syncthreads();
  for (int i = t; i < n; i += 512) {
    uint32 pk = (i < BS_CAP) ? sb[i] : pairs[beg + i];
    int j = pk >> 20;
    int p = atomicAdd(&cursor[j], 1);
    eidx[beg + p] = (int)(pk & 0xFFFFF);
  }
}

// ---- one wave per node, 4-deep MLP, nontemporal index loads
__global__ __launch_bounds__(256) void k_gather(const uint32* __restrict__ hb,
                        const int* __restrict__ row_ptr, const int* __restrict__ eidx,
                        const float* __restrict__ eps1, uint32* __restrict__ gb, int N_) {
  int w = (int)((blockIdx.x*blockDim.x + threadIdx.x) >> 6);
  w = __builtin_amdgcn_readfirstlane(w);
  int lane = threadIdx.x & 63;
  if (w >= N_) return;
  int beg = __builtin_nontemporal_load(row_ptr + w);
  int end = __builtin_nontemporal_load(row_ptr + w + 1);
  float2 a0 = {0.f,0.f}, a1 = {0.f,0.f}, a2 = {0.f,0.f}, a3 = {0.f,0.f};
  int e = beg;
  for (; e + 3 < end; e += 4) {
    int s0 = __builtin_nontemporal_load(eidx + e);
    int s1 = __builtin_nontemporal_load(eidx + e + 1);
    int s2 = __builtin_nontemporal_load(eidx + e + 2);
    int s3 = __builtin_nontemporal_load(eidx + e + 3);
    uint32 u0 = hb[(size_t)s0*64 + lane];
    uint32 u1 = hb[(size_t)s1*64 + lane];
    uint32 u2 = hb[(size_t)s2*64 + lane];
    uint32 u3 = hb[(size_t)s3*64 + lane];
    a0.x += bflo(u0); a0.y += bfhi(u0);
    a1.x += bflo(u1); a1.y += bfhi(u1);
    a2.x += bflo(u2); a2.y += bfhi(u2);
    a3.x += bflo(u3); a3.y += bfhi(u3);
  }
  for (; e < end; e++) {
    int s0 = __builtin_nontemporal_load(eidx + e);
    uint32 u0 = hb[(size_t)s0*64 + lane];
    a0.x += bflo(u0); a0.y += bfhi(u0);
  }
  float degf = (float)(end - beg);
  float e1 = eps1[0];
  uint32 hu = hb[(size_t)w*64 + lane];
  float ox = ((a0.x + a1.x) + (a2.x + a3.x)) / degf + e1 * bflo(hu);
  float oy = ((a0.y + a1.y) + (a2.y + a3.y)) / degf + e1 * bfhi(hu);
  gb[(size_t)w*64 + lane] = f2bf(ox) | (f2bf(oy) << 16);
}

// ---- y = g@W1^T via MFMA (B staged in LDS) -> per-block col sum/sumsq
__global__ __launch_bounds__(256) void k_xstat(const uint32* __restrict__ gb,
                     const uint32* __restrict__ W1b, float* __restrict__ yslab, int N_) {
  __shared__ uint32 wlds[8704];     // 128 rows x 68 uint32 (padded)
  __shared__ float wsl[4][512];
  int t = threadIdx.x;
  int l = t & 63, w = t >> 6;
  int m0 = blockIdx.x*64 + w*16;
  int lm = l & 15, lq = l >> 4;
  const uint4* gb4 = (const uint4*)gb;
  int arow = m0 + lm; if (arow > N_-1) arow = N_-1;
  U16B a[4];
  #pragma unroll
  for (int kc=0; kc<4; kc++) a[kc].u = gb4[(size_t)arow*16 + kc*4 + lq];
  #pragma unroll
  for (int half=0; half<2; half++){
    __syncthreads();
    for (int i = t; i < 2048; i += 256) {
      int r = i >> 4, q = i & 15;
      *(uint4*)&wlds[r*68 + q*4] = ((const uint4*)W1b)[(size_t)(half*128 + r)*16 + q];
    }
    __syncthreads();
    f32x4 acc[8];
    #pragma unroll
    for (int j=0; j<8; j++) acc[j] = (f32x4)0.f;
    #pragma unroll
    for (int j=0; j<8; j++){
      int rl = j*16 + lm;
      #pragma unroll
      for (int kc=0; kc<4; kc++){
        U16B b; b.u = *(const uint4*)&wlds[rl*68 + kc*16 + lq*4];
        acc[j] = __builtin_amdgcn_mfma_f32_16x16x32_bf16(a[kc].s, b.s, acc[j], 0, 0, 0);
      }
    }
    #pragma unroll
    for (int j=0; j<8; j++){
      int nt = half*8 + j;
      float s4 = 0.f, q4 = 0.f;
      #pragma unroll
      for (int r=0; r<4; r++){
        int row = m0 + lq*4 + r;
        if (row < N_) { float v = acc[j][r]; s4 += v; q4 += v*v; }
      }
      s4 += __shfl_xor(s4, 16, 64); s4 += __shfl_xor(s4, 32, 64);
      q4 += __shfl_xor(q4, 16, 64); q4 += __shfl_xor(q4, 32, 64);
      if (lq == 0) { wsl[w][nt*16+lm] = s4; wsl[w][256+nt*16+lm] = q4; }
    }
  }
  __syncthreads();
  float o0 = wsl[0][t] + wsl[1][t] + wsl[2][t] + wsl[3][t];
  float o1 = wsl[0][256+t] + wsl[1][256+t] + wsl[2][256+t] + wsl[3][256+t];
  yslab[(size_t)blockIdx.x*512 + t] = o0;
  yslab[(size_t)blockIdx.x*512 + 256 + t] = o1;
}

// ---- reduce yslab[nblk][512] -> ysum2[YG][512]
__global__ __launch_bounds__(256) void k_yreduce(const float* __restrict__ yslab,
                        float* __restrict__ ysum2, int nblk, int per) {
  int i = blockIdx.x*256 + threadIdx.x;
  if (i >= 512) return;
  int g2 = blockIdx.y;
  int k0 = g2 * per;
  int k1 = min(k0 + per, nblk);
  float s = 0.f;
  for (int k = k0; k < k1; k++) s += yslab[(size_t)k*512 + i];
  ysum2[(size_t)g2*512 + i] = s;
}

// ---- fused stats + M build: block k -> Mb[k,:] (bf16) and cbuf[k]
__global__ __launch_bounds__(256) void k_smm(const float* __restrict__ ysum2,
                        const float* __restrict__ W1, const float* __restrict__ W2,
                        const float* __restrict__ b2, const float* __restrict__ gamma,
                        const float* __restrict__ beta, ushort* __restrict__ Mb,
                        float* __restrict__ cbuf, int N_) {
  __shared__ float ws[256];
  __shared__ float red[256];
  int k = blockIdx.x, t = threadIdx.x;
  float s0 = 0.f, s1 = 0.f;
  #pragma unroll
  for (int g2 = 0; g2 < YG; g2++){
    s0 += ysum2[(size_t)g2*512 + t];
    s1 += ysum2[(size_t)g2*512 + 256 + t];
  }
  float invN = 1.f/(float)N_;
  float mean = s0*invN;
  float var = s1*invN - mean*mean;
  float sc = gamma[t]*rsqrtf(var + 1e-5f);
  float tt = beta[t] - mean*sc;
  float w2 = W2[(size_t)k*256 + t];
  ws[t] = sc*w2;
  red[t] = tt*w2;
  __syncthreads();
  for (int off=128; off>0; off>>=1){
    if (t < off) red[t] += red[t+off];
    __syncthreads();
  }
  if (t == 0) cbuf[k] = b2[k] + red[0];
  if (t < 128){
    float acc = 0.f;
    for (int j=0;j<256;j++) acc += ws[j]*W1[(size_t)j*128 + t];
    Mb[(size_t)k*128 + t] = (ushort)f2bf(acc);
  }
}

// ---- out[i,k] = g[i,:].M[k,:] + c[k]  (B staged in LDS; smem reused for st)
__global__ __launch_bounds__(256) void k_out(const uint32* __restrict__ gb,
                     const uint32* __restrict__ Mb2, const float* __restrict__ cb,
                     float* __restrict__ out, int N_) {
  __shared__ uint32 smem[8704];   // phase A: B-stage 128x68; phase B: st[4][16][132]
  int t = threadIdx.x;
  int l = t & 63, w = t >> 6;
  int m0 = blockIdx.x*64 + w*16;
  int lm = l & 15, lq = l >> 4;
  const uint4* gb4 = (const uint4*)gb;
  int arow = m0 + lm; if (arow > N_-1) arow = N_-1;
  U16B a[4];
  #pragma unroll
  for (int kc=0; kc<4; kc++) a[kc].u = gb4[(size_t)arow*16 + kc*4 + lq];
  f32x4 acc[16];
  #pragma unroll
  for (int nt=0; nt<16; nt++) acc[nt] = (f32x4)0.f;
  #pragma unroll
  for (int half=0; half<2; half++){
    __syncthreads();
    for (int i = t; i < 2048; i += 256) {
      int r = i >> 4, q = i & 15;
      *(uint4*)&smem[r*68 + q*4] = ((const uint4*)Mb2)[(size_t)(half*128 + r)*16 + q];
    }
    __syncthreads();
    #pragma unroll
    for (int j=0; j<8; j++){
      int nt = half*8 + j;
      int rl = j*16 + lm;
      #pragma unroll
      for (int kc=0; kc<4; kc++){
        U16B b; b.u = *(const uint4*)&smem[rl*68 + kc*16 + lq*4];
        acc[nt] = __builtin_amdgcn_mfma_f32_16x16x32_bf16(a[kc].s, b.s, acc[nt], 0, 0, 0);
      }
    }
  }
  __syncthreads();                     // all waves done with B before st reuse
  float* st = (float*)smem;            // [w][row][132]
  int rr = l >> 5, cc = l & 31;
  #pragma unroll
  for (int half=0; half<2; half++){
    #pragma unroll
    for (int q8=0; q8<8; q8++){
      int nt = half*8 + q8;
      float cv = cb[nt*16 + lm];
      #pragma unroll
      for (int r=0; r<4; r++)
        st[w*2112 + (lq*4+r)*132 + q8*16+lm] = acc[nt][r] + cv;
    }
    #pragma unroll
    for (int it=0; it<8; it++){
      int row = it*2 + rr;
      int gr = m0 + row;
      float4 v = *(float4*)&st[w*2112 + row*132 + cc*4];
      if (gr < N_) *(float4*)&out[(size_t)gr*256 + half*128 + cc*4] = v;
    }
  }
}

extern "C" void kernel_launch(void* const* d_in, const int* in_sizes, int n_in,
                              void* d_out, int out_size, void* d_ws, size_t ws_size,
                              hipStream_t stream) {
  const float* h     = (const float*)d_in[0];
  const int*   esrc  = (const int*)d_in[1];
  const int*   edst  = (const int*)d_in[2];
  const float* W1    = (const float*)d_in[3];
  const float* b1    = (const float*)d_in[4];  (void)b1;
  const float* W2    = (const float*)d_in[5];
  const float* b2    = (const float*)d_in[6];
  const float* gamma = (const float*)d_in[7];
  const float* beta  = (const float*)d_in[8];
  const float* eps1  = (const float*)d_in[9];
  int N = in_sizes[0] / IN_DIM;
  int E = in_sizes[1];
  int B = (N + NPB - 1) / NPB;          // 391 for N=100000
  int nxb = (N + 63) / 64;
  float* out = (float*)d_out;

  char* ws = (char*)d_ws;
  size_t off = 0;
  auto alloc = [&](size_t bytes)->char* {
    char* p = ws + off; off = align256(off + bytes); return p;
  };
  int*    gcount  = (int*)   alloc((size_t)B*4);
  int*    boff    = (int*)   alloc(((size_t)B+1)*4);
  int*    gcursor = (int*)   alloc((size_t)B*4);
  int*    row_ptr = (int*)   alloc(((size_t)N+1)*4);
  uint32* pairs   = (uint32*)alloc((size_t)E*4);
  int*    eidx    = (int*)   alloc((size_t)E*4);
  uint32* hb      = (uint32*)alloc((size_t)N*64*4);
  uint32* gb      = (uint32*)alloc((size_t)N*64*4);
  uint32* W1b     = (uint32*)alloc(256*128*2);
  float*  ysum2   = (float*) alloc((size_t)YG*512*4);
  float*  yslab   = (float*) alloc((size_t)nxb*512*4);
  float*  cbuf    = (float*) alloc(256*4);
  ushort* Mb      = (ushort*)alloc(256*128*2);
  (void)n_in; (void)out_size; (void)ws_size;

  k_zero  <<<(B+255)/256, 256, 0, stream>>>(gcount, B);
  k_prep  <<<1024, 256, 0, stream>>>(h, hb, N*IN_DIM/4, W1, W1b, edst, gcount, E, B);
  k_bscan <<<1, 256, 0, stream>>>(gcount, boff, gcursor, row_ptr, B, N);
  {
    int fbblk = (E + FB_CAP - 101) / (FB_CAP - 100);
    if (fbblk < 512) fbblk = 512;
    k_bfill<<<fbblk, 256, 0, stream>>>(esrc, edst, gcursor, pairs, E, B);
  }
  k_bsort <<<B, 512, 0, stream>>>(pairs, boff, row_ptr, eidx, N);
  k_gather<<<(N+3)/4, 256, 0, stream>>>(hb, row_ptr, eidx, eps1, gb, N);
  k_xstat <<<nxb, 256, 0, stream>>>(gb, W1b, yslab, N);
  {
    int per = (nxb + YG - 1) / YG;
    dim3 rgrid(2, YG);
    k_yreduce<<<rgrid, 256, 0, stream>>>(yslab, ysum2, nxb, per);
  }
  k_smm   <<<256, 256, 0, stream>>>(ysum2, W1, W2, b2, gamma, beta, Mb, cbuf, N);
  k_out   <<<(N+63)/64, 256, 0, stream>>>(gb, (const uint32*)Mb, cbuf, out, N);
}